// Round 2
// baseline (107.695 us; speedup 1.0000x reference)
//
#include <hip/hip_runtime.h>
#include <math.h>
#include <utility>

#define BB 64
#define NN 512
#define DD 32
#define ZD 34            // DD + 2 (x..., t, y)
#define NE 595           // ZD*(ZD+1)/2 upper-triangular entries
#define WIN 8
#define NW 64            // NN / NW windows
#define WACT 60          // active windows w = 4..63 (n <= 31 is rank-deficient -> 0)

// fused gram+scan geometry (v2: 2x2 register tiles, 64-row segments)
#define SEG 8            // segments per batch (64 rows each)
#define RS 64            // rows per segment
#define KWS 8            // windows per segment
#define NT 153           // 2x2 tiles covering the 34x34 upper triangle (17*18/2)
#define PSTRIDE 9        // 8 exclusive in-segment snapshots + segment total

// tile t -> (ti,tj), ti <= tj, row-major upper triangle of 17 x 17
__device__ inline void tile2ij(int t, int& i, int& j) {
    int ii = 0, rem = t;
    while (rem >= 17 - ii) { rem -= (17 - ii); ++ii; }
    i = ii; j = ii + rem;
}

// e(i,j) in the 34-wide upper triangle
__device__ __forceinline__ int eidx(int i, int j) {
    return i * ZD - (i * (i - 1)) / 2 + (j - i);
}

// ---- recursive struct-of-scalars: SROA-guaranteed register residency ----
template<int N> struct Pack { Pack<N - 1> head; float v; };
template<> struct Pack<1> { float v; };
template<int I, int N> __device__ __forceinline__ float& pget(Pack<N>& p) {
    static_assert(I < N, "oob");
    if constexpr (I == N - 1) return p.v;
    else return pget<I, N - 1>(p.head);
}

__device__ __forceinline__ float rdlane(float x, int srclane) {
    return __int_as_float(__builtin_amdgcn_readlane(__float_as_int(x), srclane));
}

// Fused window-partial + prefix-scan, 2x2-tiled. Block = (b, segment).
// Thread owns a 2x2 tile of the Gram triangle: per row, 2 ds_read_b64 feed
// 4 fp64 FMAs (4x fewer LDS instructions than entry-per-thread). Emits 8
// exclusive window snapshots + segment total to P[b][g][9][NE]. Cross-segment
// totals are combined in dml_solve's staging (<= 7 L2-resident adds/element).
// Folds output init: logs[.]=0 everywhere and means=0 for n < 32.
__global__ __launch_bounds__(256) void dml_gram(const float* __restrict__ xtys,
                                                float* __restrict__ P,
                                                float* __restrict__ out) {
    const int t   = threadIdx.x;
    const int blk = blockIdx.x;                  // b * SEG + g
    const int g   = blk % SEG;
    const int b   = blk / SEG;

    const int gid = blk * 256 + t;
    if (gid < BB * NN) out[BB * NN + gid] = 0.0f;
    if (gid < BB * DD) out[(gid >> 5) * NN + (gid & 31)] = 0.0f;

    __shared__ float2 zs2[RS * 17];              // 64 rows x 34 floats, 8704 B
    const float2* src2 = (const float2*)(xtys + ((size_t)b * NN + (size_t)g * RS) * ZD);
    for (int u = t; u < RS * 17; u += 256) zs2[u] = src2[u];
    __syncthreads();

    if (t < NT) {
        int ti, tj;
        tile2ij(t, ti, tj);
        const int i    = 2 * ti, j = 2 * tj;
        const bool dia = (ti == tj);
        const int eA   = eidx(i, j);                       // (i,j), (i,j+1)=eA+1
        const int eB   = dia ? eidx(i + 1, i + 1)          // (i+1,i+1)
                             : eidx(i + 1, j);             // (i+1,j), (i+1,j+1)=eB+1

        float* pdst = P + (size_t)blk * PSTRIDE * NE;
        double a00 = 0.0, a01 = 0.0, a10 = 0.0, a11 = 0.0;
#pragma unroll
        for (int k = 0; k < KWS; ++k) {
            float* ps = pdst + k * NE;                     // exclusive snapshot
            ps[eA]     = (float)a00;
            ps[eA + 1] = (float)a01;
            if (dia) { ps[eB] = (float)a11; }
            else     { ps[eB] = (float)a10; ps[eB + 1] = (float)a11; }
#pragma unroll
            for (int s8 = 0; s8 < WIN; ++s8) {
                const int s = k * WIN + s8;
                float2 xa = zs2[s * 17 + ti];
                float2 xb = zs2[s * 17 + tj];
                a00 = fma((double)xa.x, (double)xb.x, a00);
                a01 = fma((double)xa.x, (double)xb.y, a01);
                a10 = fma((double)xa.y, (double)xb.x, a10);
                a11 = fma((double)xa.y, (double)xb.y, a11);
            }
        }
        float* ps = pdst + KWS * NE;                       // segment total
        ps[eA]     = (float)a00;
        ps[eA + 1] = (float)a01;
        if (dia) { ps[eB] = (float)a11; }
        else     { ps[eB] = (float)a10; ps[eB + 1] = (float)a11; }
    }
}

// ---- solve helpers: lane = COLUMN j of the full symmetric 48x48 bordered
// matrix [[G0, W],[W^T, 0]], W = [x_1..x_8, Xtt0, Xty0]; A[r] = M[r][j].
// Elimination step k: all cross-lane values are wave-uniform (from lane k)
// -> v_readlane (2-cyc VALU, SGPR result), zero LDS/shuffle latency.
// Rows/cols <= k self-neutralize (t = invp*M[k][j] = 0 for eliminated j).
// Rows 42..47 are identically zero for every column -> elimination stops at 42.

template<int R> __device__ __forceinline__
float initval(int j, const float* snL, const float* zb) {
    if constexpr (R < DD) {
        float v = 0.0f;
        if (j < DD) {
            int i0 = (R < j) ? R : j;
            int j0 = (R < j) ? j : R;
            v = snL[i0 * ZD - (i0 * (i0 - 1)) / 2 + (j0 - i0)];
        } else if (j < DD + WIN) {
            v = zb[(j - DD) * ZD + R];
        } else if (j == 40) {
            v = snL[R * ZD - (R * (R - 1)) / 2 + (DD - R)];       // Xtt0[R]
        } else if (j == 41) {
            v = snL[R * ZD - (R * (R - 1)) / 2 + (DD + 1 - R)];   // Xty0[R]
        }
        return v;
    } else if constexpr (R < DD + WIN) {
        return (j < DD) ? zb[(R - DD) * ZD + j] : 0.0f;
    } else if constexpr (R == 40) {
        return (j < DD) ? snL[j * ZD - (j * (j - 1)) / 2 + (DD - j)] : 0.0f;
    } else if constexpr (R == 41) {
        return (j < DD) ? snL[j * ZD - (j * (j - 1)) / 2 + (DD + 1 - j)] : 0.0f;
    } else {
        return 0.0f;
    }
}
template<int R> __device__ __forceinline__
void init_rec(Pack<48>& A, int j, const float* snL, const float* zb) {
    if constexpr (R < 48) {
        pget<R>(A) = initval<R>(j, snL, zb);
        init_rec<R + 1>(A, j, snL, zb);
    }
}

template<int K, int R> __device__ __forceinline__
void elim_rows(Pack<48>& A, float t) {
    if constexpr (R < DD + 10) {               // rows 42..47 are always zero
        float fr = rdlane(pget<R>(A), K);      // M[R][K], wave-uniform
        pget<R>(A) = fmaf(-fr, t, pget<R>(A));
        elim_rows<K, R + 1>(A, t);
    }
}
template<int K> __device__ __forceinline__
void elim_step(Pack<48>& A) {
    float piv  = rdlane(pget<K>(A), K);        // M[K][K]
    float invp = (piv > 1e-30f) ? 1.0f / piv : 0.0f;
    float t    = invp * pget<K>(A);            // invp * M[K][j]; 0 for done cols
    elim_rows<K, K + 1>(A, t);
}
template<int... Ks> __device__ __forceinline__
void elim_all(Pack<48>& A, std::integer_sequence<int, Ks...>) {
    ((elim_step<Ks>(A)), ...);
}

template<int R> __device__ __forceinline__
void kdump(Pack<48>& A, float* Kl, int c) {    // lanes 32..41: column c of K
    if constexpr (R < DD + 10) {
        Kl[(R - DD) * 10 + c] = -pget<R>(A);
        kdump<R + 1>(A, Kl, c);
    }
}

// ---- per-lane 8x8 GJ (one system per lane, zero cross-lane traffic) ----
template<int L> __device__ __forceinline__
void tinit(Pack<96>& T, int m, const float* Kl, const float* zb) {
    if constexpr (L < 96) {
        constexpr int I = L / 12, J = L % 12;
        float v;
        if constexpr (J < 8) {
            float kij = (I < m && J < m) ? Kl[I * 10 + J] : 0.0f;
            v = kij + ((I == J) ? 1.0f : 0.0f);
        } else if constexpr (J == 8)  v = (I < m) ? Kl[I * 10 + 8] : 0.0f;   // KUp
        else if constexpr (J == 9)    v = (I < m) ? zb[I * ZD + DD] : 0.0f;  // t_i
        else if constexpr (J == 10)   v = (I < m) ? Kl[I * 10 + 9] : 0.0f;   // KUq
        else                          v = (I < m) ? zb[I * ZD + DD + 1] : 0.0f; // y_i
        pget<L>(T) = v;
        tinit<L + 1>(T, m, Kl, zb);
    }
}
template<int K, int I, int J> __device__ __forceinline__
void gj_cols(Pack<96>& T, float f) {
    if constexpr (J < 12) {
        pget<I * 12 + J>(T) = fmaf(-f, pget<K * 12 + J>(T), pget<I * 12 + J>(T));
        gj_cols<K, I, J + 1>(T, f);
    }
}
template<int K, int I> __device__ __forceinline__
void gj_rows(Pack<96>& T, float invp) {
    if constexpr (I < 8) {
        if constexpr (I != K) {
            float f = pget<I * 12 + K>(T) * invp;
            gj_cols<K, I, K + 1>(T, f);
        }
        gj_rows<K, I + 1>(T, invp);
    }
}
template<int K> __device__ __forceinline__
void gj_step(Pack<96>& T) {
    float piv  = pget<K * 12 + K>(T);
    float invp = (piv > 1e-30f || piv < -1e-30f) ? 1.0f / piv : 0.0f;
    gj_rows<K, 0>(T, invp);
}
template<int... Ks> __device__ __forceinline__
void gj_all(Pack<96>& T, std::integer_sequence<int, Ks...>) {
    ((gj_step<Ks>(T)), ...);
}
template<int I> __device__ __forceinline__
void finacc(Pack<96>& T, int m, const float* Kl, const float* zb,
            double& dt, double& nt) {
    if constexpr (I < 8) {
        if (I < m) {
            float di   = pget<I * 12 + I>(T);
            float dinv = (di > 1e-30f || di < -1e-30f) ? 1.0f / di : 0.0f;
            double s1 = (double)(pget<I * 12 + 8>(T) * dinv);
            double s2 = (double)(pget<I * 12 + 9>(T) * dinv);
            double r1 = (double)(pget<I * 12 + 10>(T) * dinv);
            double r2 = (double)(pget<I * 12 + 11>(T) * dinv);
            double g  = (double)Kl[80 + I] - (double)zb[I * ZD + DD]; // KpU_i - t_i
            dt += g * (s1 - s2);
            nt += g * (r1 - r2);
        }
        finacc<I + 1>(T, m, Kl, zb, dt, nt);
    }
}

// ONE WAVE per (b, w>=4). Snapshot Sn[w] is assembled during LDS staging from
// the segment pieces: Sn[w] = piece[g][k] + sum_{g'<g} total[g'], g=w>>3,
// k=w&7 (coalesced L2-resident reads, <=7 adds/element). Then readlane-based
// column elimination, and one 8x8 GJ system PER LANE (lanes 0..7) in regs.
//   den = Stt0 - Kpp + sum_i (KpU_i - t_i)(s1_i - s2_i), s1=S^-1 KUp, s2=S^-1 t
//   num = Sty0 - Kpq + sum_i (KpU_i - t_i)(r1_i - r2_i), r1=S^-1 KUq, r2=S^-1 y
__global__ __launch_bounds__(64) void dml_solve(const float* __restrict__ xtys,
                                                const float* __restrict__ P,
                                                float* __restrict__ out) {
    const int id   = blockIdx.x;
    const int w    = (id % WACT) + 4;
    const int b    = id / WACT;
    const int lane = threadIdx.x;
    const int g    = w >> 3;
    const int k    = w & 7;

    __shared__ float snL[NE];
    __shared__ float zb[WIN * ZD];
    __shared__ float Kl[100];            // K = W^T G0^-1 W (10x10)

    const float* pb  = P + (size_t)b * SEG * PSTRIDE * NE;
    const float* src = xtys + ((size_t)b * NN + (size_t)w * WIN) * ZD;
    for (int u = lane; u < NE; u += 64) {
        float v = pb[(size_t)(g * PSTRIDE + k) * NE + u];
        for (int g2 = 0; g2 < g; ++g2)
            v += pb[(size_t)(g2 * PSTRIDE + KWS) * NE + u];
        snL[u] = v;
    }
    for (int u = lane; u < WIN * ZD; u += 64) zb[u] = src[u];
    __syncthreads();

    Pack<48> A;
    init_rec<0>(A, lane, snL, zb);       // lanes >= 42 (incl. 48..63) get zeros

    elim_all(A, std::make_integer_sequence<int, DD>{});

    if (lane >= DD && lane < DD + 10) kdump<DD>(A, Kl, lane - DD);
    __syncthreads();

    if (lane < 8) {
        const int m = lane + 1;          // system l = lane: n = 8w + lane
        Pack<96> T;
        tinit<0>(T, m, Kl, zb);
        gj_all(T, std::make_integer_sequence<int, 8>{});
        double dt = 0.0, nt = 0.0;
        finacc<0>(T, m, Kl, zb, dt, nt);
        double Stt0 = (double)snL[592];
        double Sty0 = (double)snL[593];
        double den  = Stt0 - (double)Kl[88] + dt;   // Stt0 - Kpp + dterm
        double num  = Sty0 - (double)Kl[89] + nt;   // Sty0 - Kpq + nterm
        double val  = (den > 0.0) ? num / den : 0.0;
        if (!isfinite(val)) val = 0.0;
        out[b * NN + w * WIN + lane] = (float)val;
    }
}

extern "C" void kernel_launch(void* const* d_in, const int* in_sizes, int n_in,
                              void* d_out, int out_size, void* d_ws, size_t ws_size,
                              hipStream_t stream) {
    const float* xtys = (const float*)d_in[0];
    float* out = (float*)d_out;
    float* P = (float*)d_ws;   // [BB][SEG][9][NE] fp32 = 10.97 MB

    hipLaunchKernelGGL(dml_gram, dim3(BB * SEG), dim3(256), 0, stream, xtys, P, out);
    hipLaunchKernelGGL(dml_solve, dim3(BB * WACT), dim3(64), 0, stream, xtys, P, out);
}